// Round 14
// baseline (2559.096 us; speedup 1.0000x reference)
//
#include <hip/hip_runtime.h>
#include <stdint.h>

namespace {

constexpr int NIN = 21;
constexpr int T   = 3000;
constexpr int NB  = 2;     // batches per block -> 256 blocks = 1 per CU

typedef _Float16 f16x8 __attribute__((ext_vector_type(8)));
typedef float    f32x4 __attribute__((ext_vector_type(4)));

__device__ __forceinline__ float frcp(float x){ return __builtin_amdgcn_rcpf(x); }
__device__ __forceinline__ float sigm(float v){ return frcp(1.0f + __expf(-v)); }
__device__ __forceinline__ float tanh_fast(float v){
    return fmaf(-2.0f, frcp(__expf(2.0f*v) + 1.0f), 1.0f);
}

template<int CTRL>
__device__ __forceinline__ float dppf(float v){
    return __int_as_float(__builtin_amdgcn_update_dpp(
        0, __float_as_int(v), CTRL, 0xF, 0xF, true));
}
// Verified family: row_ror:J => out[i]=in[(i-J)&15]; row_shr:N => out[i]=in[i-N]
constexpr int SHR4  = 0x114;
constexpr int SHR8  = 0x118;
constexpr int SHR12 = 0x11C;
constexpr int ROR14 = 0x12E;   // out[i] = in[(i+2)&15]

#define MFMA(A,B,C) __builtin_amdgcn_mfma_f32_16x16x32_f16((A),(B),(C),0,0,0)

__device__ __forceinline__ f16x8 ldfrag(const _Float16* p){
    return *reinterpret_cast<const f16x8*>(p);   // aligned 16B LDS read
}
__device__ __forceinline__ void cvt8v(const float* s, f16x8& hi, f16x8& lo){
    #pragma unroll
    for (int j=0;j<8;++j){
        float f = s[j];
        _Float16 h = (_Float16)f;
        hi[j] = h;
        lo[j] = (_Float16)(f - (float)h);
    }
}
__device__ __forceinline__ void spin_ge(volatile uint32_t* p, uint32_t tgt){
    while (*p < tgt) __builtin_amdgcn_s_sleep(2);
}

// Verified MFMA layout (r8-r13): D[n][m] = sum_k A[n][k]*B[m][k]
//   A-frag: n = lane&15, k = 32*kc + 8*(lane>>4) + j ; B same; D: m=lane&15, n=4*(lane>>4)+v
// B cols: 0,1 = batch0/1 Hhi; 2,3 = batch0/1 Hlo; >=4 zero.
// acc = MFMA(Whi,B)+MFMA(Wlo,B); gate = D[:,m]+D[:,m+2]  (bias halved in C-init).
// Spread rows to lanes via row_shr, fold cols via row_ror:14 (verified r12/r13).
__device__ __forceinline__ void spread_fold(const f32x4& a0, const f32x4& a1,
                                            const f32x4& a2, const f32x4& a3,
                                            int q, float& g0, float& g1,
                                            float& g2, float& g3){
    float u1,u2,u3;
    u1=dppf<SHR4>(a0[1]); u2=dppf<SHR8>(a0[2]); u3=dppf<SHR12>(a0[3]);
    g0=(q==0)?a0[0]:(q==1)?u1:(q==2)?u2:u3;
    u1=dppf<SHR4>(a1[1]); u2=dppf<SHR8>(a1[2]); u3=dppf<SHR12>(a1[3]);
    g1=(q==0)?a1[0]:(q==1)?u1:(q==2)?u2:u3;
    u1=dppf<SHR4>(a2[1]); u2=dppf<SHR8>(a2[2]); u3=dppf<SHR12>(a2[3]);
    g2=(q==0)?a2[0]:(q==1)?u1:(q==2)?u2:u3;
    u1=dppf<SHR4>(a3[1]); u2=dppf<SHR8>(a3[2]); u3=dppf<SHR12>(a3[3]);
    g3=(q==0)?a3[0]:(q==1)?u1:(q==2)?u2:u3;
    g0 += dppf<ROR14>(g0);
    g1 += dppf<ROR14>(g1);
    g2 += dppf<ROR14>(g2);
    g3 += dppf<ROR14>(g3);
}

__launch_bounds__(512, 1)
__global__ void lstm_flag(const float* __restrict__ x,
                          const float* __restrict__ Wih0, const float* __restrict__ Whh0,
                          const float* __restrict__ bih0, const float* __restrict__ bhh0,
                          const float* __restrict__ Wih1, const float* __restrict__ Whh1,
                          const float* __restrict__ bih1, const float* __restrict__ bhh1,
                          const float* __restrict__ Wfc,  const float* __restrict__ bfc,
                          float* __restrict__ out)
{
    const int tid  = threadIdx.x;
    const int lane = tid & 63;
    const int wid  = tid >> 6;
    const int c    = lane >> 4;
    const int mcol = lane & 15;
    const int b0   = blockIdx.x * NB;
    const bool isL0 = (wid < 4);
    const int  w    = wid & 3;

    // h1 produced by L0 group, consumed by L0 (next step) and L1 (lagged): mod-4
    __shared__ __align__(16) _Float16 h1p[4][2][NB][72];
    // h2 private to L1 group: mod-2
    __shared__ __align__(16) _Float16 h2p[2][2][NB][72];
    __shared__ __align__(16) _Float16 xp [4][2][NB][40];
    __shared__ uint32_t l0cnt, l1cnt;   // monotonic: 4 increments per completed step

    // ----- weights (identical to r13): unified slots -----
    f16x8 Whi[4][4], Wlo[4][4];
    f32x4 bias4[4];
    {
        float tmp[8];
        #pragma unroll
        for (int tau = 0; tau < 4; ++tau) {
            const int n = 64*tau + 16*w + mcol;
            if (isL0) {
                #pragma unroll
                for (int j=0;j<8;++j){ int k=8*c+j; tmp[j] = (k<NIN)? Wih0[n*NIN+k] : 0.0f; }
                cvt8v(tmp, Whi[tau][0], Wlo[tau][0]);
                #pragma unroll
                for (int kc=0;kc<2;++kc){
                    #pragma unroll
                    for (int j=0;j<8;++j) tmp[j] = Whh0[n*64 + 32*kc + 8*c + j];
                    cvt8v(tmp, Whi[tau][1+kc], Wlo[tau][1+kc]);
                }
                #pragma unroll
                for (int j=0;j<8;++j){ Whi[tau][3][j]=(_Float16)0.f; Wlo[tau][3][j]=(_Float16)0.f; }
            } else {
                #pragma unroll
                for (int kc=0;kc<2;++kc){
                    #pragma unroll
                    for (int j=0;j<8;++j) tmp[j] = Wih1[n*64 + 32*kc + 8*c + j];
                    cvt8v(tmp, Whi[tau][kc], Wlo[tau][kc]);
                }
                #pragma unroll
                for (int kc=0;kc<2;++kc){
                    #pragma unroll
                    for (int j=0;j<8;++j) tmp[j] = Whh1[n*64 + 32*kc + 8*c + j];
                    cvt8v(tmp, Whi[tau][2+kc], Wlo[tau][2+kc]);
                }
            }
            const int nb = 64*tau + 16*w + 4*c;
            #pragma unroll
            for (int v=0; v<4; ++v)
                bias4[tau][v] = 0.5f * (isL0 ? (bih0[nb+v] + bhh0[nb+v])
                                             : (bih1[nb+v] + bhh1[nb+v]));
        }
    }

    // ----- LDS zero init (h1p[3], h2p[1] double as the t=0 zero states) -----
    {
        uint32_t* p1 = (uint32_t*)&h1p[0][0][0][0];   // 576 u32
        uint32_t* p2 = (uint32_t*)&h2p[0][0][0][0];   // 288 u32
        uint32_t* p3 = (uint32_t*)&xp[0][0][0][0];    // 320 u32
        for (int i = tid; i < 576; i += 512) p1[i] = 0u;
        if (tid < 288) p2[tid] = 0u;
        if (tid < 320) p3[tid] = 0u;
        if (tid == 0){ l0cnt = 0u; l1cnt = 0u; }
    }
    __syncthreads();

    // ----- x staging: waves 0,1 (subset of L0 group), lane<NIN -----
    const bool stg = (wid < 2) && (lane < NIN);
    const float* xsrc = x + (size_t)(b0 + (wid & 1)) * T * NIN + lane;
    float xrA = 0.f, xrB = 0.f;
    if (stg){
        float x0 = xsrc[0], x1 = xsrc[NIN];
        _Float16 hh0 = (_Float16)x0;
        xp[0][0][wid][lane] = hh0;
        xp[0][1][wid][lane] = (_Float16)(x0 - (float)hh0);
        _Float16 hh1 = (_Float16)x1;
        xp[1][0][wid][lane] = hh1;
        xp[1][1][wid][lane] = (_Float16)(x1 - (float)hh1);
        xrA = xsrc[(size_t)2*NIN];
        xrB = xsrc[(size_t)3*NIN];
    }
    __syncthreads();

    float cst = 0.f;
    const int q  = mcol >> 2;
    const int bt = mcol & 1;
    const int pl = (mcol >> 1) & 1;

    if (isL0) {
        // =================== layer-0 producer loop ===================
        f16x8 Bf0, Bf1, Bf2;
        #pragma unroll
        for (int j=0;j<8;++j){ Bf0[j]=(_Float16)0.f; Bf1[j]=(_Float16)0.f; Bf2[j]=(_Float16)0.f; }
        for (int t = 0; t < T; ++t) {
            float xnew = 0.f;
            if (stg && (t + 4 < T)) xnew = xsrc[(size_t)(t+4)*NIN];  // issue early
            if (t > 0)  spin_ge(&l0cnt, 4u*(uint32_t)t);            // peers wrote h1(t-1)
            if (t >= 4) spin_ge(&l1cnt, 4u*(uint32_t)(t-3));        // slot t&3 consumed
            if (mcol < 4) {
                Bf0 = ldfrag(&xp[t & 3][pl][bt][8*c]);
                Bf1 = ldfrag(&h1p[(t+3) & 3][pl][bt][8*c]);         // h1(t-1)
                Bf2 = ldfrag(&h1p[(t+3) & 3][pl][bt][32 + 8*c]);
            }
            f32x4 a0 = bias4[0], a1 = bias4[1], a2 = bias4[2], a3 = bias4[3];
            __builtin_amdgcn_s_setprio(1);
            a0=MFMA(Whi[0][0],Bf0,a0); a1=MFMA(Whi[1][0],Bf0,a1);
            a2=MFMA(Whi[2][0],Bf0,a2); a3=MFMA(Whi[3][0],Bf0,a3);
            a0=MFMA(Wlo[0][0],Bf0,a0); a1=MFMA(Wlo[1][0],Bf0,a1);
            a2=MFMA(Wlo[2][0],Bf0,a2); a3=MFMA(Wlo[3][0],Bf0,a3);
            a0=MFMA(Whi[0][1],Bf1,a0); a1=MFMA(Whi[1][1],Bf1,a1);
            a2=MFMA(Whi[2][1],Bf1,a2); a3=MFMA(Whi[3][1],Bf1,a3);
            a0=MFMA(Wlo[0][1],Bf1,a0); a1=MFMA(Wlo[1][1],Bf1,a1);
            a2=MFMA(Wlo[2][1],Bf1,a2); a3=MFMA(Wlo[3][1],Bf1,a3);
            a0=MFMA(Whi[0][2],Bf2,a0); a1=MFMA(Whi[1][2],Bf2,a1);
            a2=MFMA(Whi[2][2],Bf2,a2); a3=MFMA(Whi[3][2],Bf2,a3);
            a0=MFMA(Wlo[0][2],Bf2,a0); a1=MFMA(Wlo[1][2],Bf2,a1);
            a2=MFMA(Wlo[2][2],Bf2,a2); a3=MFMA(Wlo[3][2],Bf2,a3);
            __builtin_amdgcn_s_setprio(0);
            float g0,g1,g2,g3;
            spread_fold(a0,a1,a2,a3,q,g0,g1,g2,g3);
            if ((mcol & 2) == 0) {
                const int u = 16*w + 4*c + q;
                float i_=sigm(g0), f_=sigm(g1), gg=tanh_fast(g2), o_=sigm(g3);
                cst = fmaf(f_, cst, i_*gg);
                float h = o_ * tanh_fast(cst);
                _Float16 hh = (_Float16)h;
                h1p[t & 3][0][bt][u] = hh;
                h1p[t & 3][1][bt][u] = (_Float16)(h - (float)hh);
            }
            if (stg){
                if (t + 2 < T){
                    _Float16 hh = (_Float16)xrA;
                    xp[(t+2)&3][0][wid][lane] = hh;
                    xp[(t+2)&3][1][wid][lane] = (_Float16)(xrA - (float)hh);
                }
                xrA = xrB; xrB = xnew;
            }
            __threadfence_block();                    // drain LDS before publishing
            if (lane == 0) atomicAdd(&l0cnt, 1u);
        }
    } else {
        // =================== layer-1 consumer loop ===================
        f16x8 Bf0, Bf1, Bf2, Bf3;
        #pragma unroll
        for (int j=0;j<8;++j){ Bf0[j]=(_Float16)0.f; Bf1[j]=(_Float16)0.f;
                               Bf2[j]=(_Float16)0.f; Bf3[j]=(_Float16)0.f; }
        for (int s = 0; s < T; ++s) {
            spin_ge(&l0cnt, 4u*(uint32_t)(s+1));      // h1(s) ready
            if (s > 0) spin_ge(&l1cnt, 4u*(uint32_t)s);
            if (mcol < 4) {
                Bf0 = ldfrag(&h1p[s & 3][pl][bt][8*c]);
                Bf1 = ldfrag(&h1p[s & 3][pl][bt][32 + 8*c]);
                Bf2 = ldfrag(&h2p[(s+1) & 1][pl][bt][8*c]);         // h2(s-1)
                Bf3 = ldfrag(&h2p[(s+1) & 1][pl][bt][32 + 8*c]);
            }
            f32x4 a0 = bias4[0], a1 = bias4[1], a2 = bias4[2], a3 = bias4[3];
            __builtin_amdgcn_s_setprio(1);
            a0=MFMA(Whi[0][0],Bf0,a0); a1=MFMA(Whi[1][0],Bf0,a1);
            a2=MFMA(Whi[2][0],Bf0,a2); a3=MFMA(Whi[3][0],Bf0,a3);
            a0=MFMA(Wlo[0][0],Bf0,a0); a1=MFMA(Wlo[1][0],Bf0,a1);
            a2=MFMA(Wlo[2][0],Bf0,a2); a3=MFMA(Wlo[3][0],Bf0,a3);
            a0=MFMA(Whi[0][1],Bf1,a0); a1=MFMA(Whi[1][1],Bf1,a1);
            a2=MFMA(Whi[2][1],Bf1,a2); a3=MFMA(Whi[3][1],Bf1,a3);
            a0=MFMA(Wlo[0][1],Bf1,a0); a1=MFMA(Wlo[1][1],Bf1,a1);
            a2=MFMA(Wlo[2][1],Bf1,a2); a3=MFMA(Wlo[3][1],Bf1,a3);
            a0=MFMA(Whi[0][2],Bf2,a0); a1=MFMA(Whi[1][2],Bf2,a1);
            a2=MFMA(Whi[2][2],Bf2,a2); a3=MFMA(Whi[3][2],Bf2,a3);
            a0=MFMA(Wlo[0][2],Bf2,a0); a1=MFMA(Wlo[1][2],Bf2,a1);
            a2=MFMA(Wlo[2][2],Bf2,a2); a3=MFMA(Wlo[3][2],Bf2,a3);
            a0=MFMA(Whi[0][3],Bf3,a0); a1=MFMA(Whi[1][3],Bf3,a1);
            a2=MFMA(Whi[2][3],Bf3,a2); a3=MFMA(Whi[3][3],Bf3,a3);
            a0=MFMA(Wlo[0][3],Bf3,a0); a1=MFMA(Wlo[1][3],Bf3,a1);
            a2=MFMA(Wlo[2][3],Bf3,a2); a3=MFMA(Wlo[3][3],Bf3,a3);
            __builtin_amdgcn_s_setprio(0);
            float g0,g1,g2,g3;
            spread_fold(a0,a1,a2,a3,q,g0,g1,g2,g3);
            if ((mcol & 2) == 0) {
                const int u = 16*w + 4*c + q;
                float i_=sigm(g0), f_=sigm(g1), gg=tanh_fast(g2), o_=sigm(g3);
                cst = fmaf(f_, cst, i_*gg);
                float h = o_ * tanh_fast(cst);
                _Float16 hh = (_Float16)h;
                h2p[s & 1][0][bt][u] = hh;
                h2p[s & 1][1][bt][u] = (_Float16)(h - (float)hh);
            }
            __threadfence_block();
            if (lane == 0) atomicAdd(&l1cnt, 1u);
        }
    }
    __syncthreads();

    // ---------------- FC epilogue: out[b] = dot(h2(T-1), Wfc) + bfc ----------
    if (wid < NB) {
        float hv = (float)h2p[(T-1) & 1][0][wid][lane]
                 + (float)h2p[(T-1) & 1][1][wid][lane];
        float val = hv * Wfc[lane];
        #pragma unroll
        for (int off = 32; off > 0; off >>= 1)
            val += __shfl_down(val, off, 64);
        if (lane == 0) out[b0 + wid] = val + bfc[0];
    }
}

} // namespace

extern "C" void kernel_launch(void* const* d_in, const int* in_sizes, int n_in,
                              void* d_out, int out_size, void* d_ws, size_t ws_size,
                              hipStream_t stream)
{
    const float* x    = (const float*)d_in[0];
    const float* Wih0 = (const float*)d_in[1];
    const float* Whh0 = (const float*)d_in[2];
    const float* bih0 = (const float*)d_in[3];
    const float* bhh0 = (const float*)d_in[4];
    const float* Wih1 = (const float*)d_in[5];
    const float* Whh1 = (const float*)d_in[6];
    const float* bih1 = (const float*)d_in[7];
    const float* bhh1 = (const float*)d_in[8];
    const float* Wfc  = (const float*)d_in[9];
    const float* bfc  = (const float*)d_in[10];
    float* out = (float*)d_out;

    hipLaunchKernelGGL(lstm_flag, dim3(512 / NB), dim3(512), 0, stream,
                       x, Wih0, Whh0, bih0, bhh0, Wih1, Whh1, bih1, bhh1,
                       Wfc, bfc, out);
}

// Round 15
// 2154.768 us; speedup vs baseline: 1.1876x; 1.1876x over previous
//
#include <hip/hip_runtime.h>
#include <stdint.h>

namespace {

constexpr int NIN = 21;
constexpr int T   = 3000;
constexpr int NB  = 2;     // batches per block -> 256 blocks = 1 per CU

typedef _Float16 f16x8 __attribute__((ext_vector_type(8)));
typedef float    f32x4 __attribute__((ext_vector_type(4)));

__device__ __forceinline__ float frcp(float x){ return __builtin_amdgcn_rcpf(x); }
__device__ __forceinline__ float sigm(float v){ return frcp(1.0f + __expf(-v)); }
__device__ __forceinline__ float tanh_fast(float v){
    return fmaf(-2.0f, frcp(__expf(2.0f*v) + 1.0f), 1.0f);
}

template<int CTRL>
__device__ __forceinline__ float dppf(float v){
    return __int_as_float(__builtin_amdgcn_update_dpp(
        0, __float_as_int(v), CTRL, 0xF, 0xF, true));
}
// Verified family: row_ror:J => out[i] = in[(i-J)&15]; row_shr:N => out[i] = in[i-N]
constexpr int SHR4  = 0x114;
constexpr int SHR8  = 0x118;
constexpr int SHR12 = 0x11C;
constexpr int ROR14 = 0x12E;   // out[i] = in[(i+2)&15]

#define MFMA(A,B,C) __builtin_amdgcn_mfma_f32_16x16x32_f16((A),(B),(C),0,0,0)

__device__ __forceinline__ f16x8 ldfrag(const _Float16* p){
    return *reinterpret_cast<const f16x8*>(p);   // aligned 16B LDS read
}
__device__ __forceinline__ void cvt8h(const float* s, f16x8& hi){
    #pragma unroll
    for (int j=0;j<8;++j) hi[j] = (_Float16)s[j];   // round-to-nearest
}

// Verified MFMA layout (r8-r13): D[n][m] = sum_k A[n][k]*B[m][k]
//   A-frag: n = lane&15, k = 32*kc + 8*(lane>>4) + j
//   B-frag: m = lane&15, k = 32*kc + 8*(lane>>4) + j
//   D:      m = lane&15, n = 4*(lane>>4) + v
// B cols: 0,1 = batch0/1 Hhi; 2,3 = batch0/1 Hlo; >=4 zero.
// r15 change: W is f16 hi-only (Wlo MFMA pass dropped; |wlo·h| sums ~6e-5/gate,
// recurrent accumulation ~1e-4 vs 2.37e-3 threshold). Hlo cols are free, kept.
// gate = D[:,m] + D[:,m+2] = Whi·(Hhi+Hlo).  Bias halved in C-init (both
// summed columns carry it).
__launch_bounds__(512, 2)
__global__ void lstm_mf6(const float* __restrict__ x,
                         const float* __restrict__ Wih0, const float* __restrict__ Whh0,
                         const float* __restrict__ bih0, const float* __restrict__ bhh0,
                         const float* __restrict__ Wih1, const float* __restrict__ Whh1,
                         const float* __restrict__ bih1, const float* __restrict__ bhh1,
                         const float* __restrict__ Wfc,  const float* __restrict__ bfc,
                         float* __restrict__ out)
{
    const int tid  = threadIdx.x;
    const int lane = tid & 63;
    const int wid  = tid >> 6;
    const int c    = lane >> 4;     // k-subchunk 0..3
    const int mcol = lane & 15;
    const int b0   = blockIdx.x * NB;
    const bool isL0 = (wid < 4);
    const int  w    = wid & 3;      // unit range [16w, 16w+16)

    // hi/lo f16 planes, padded +8 (keeps 16B alignment, spreads banks)
    __shared__ __align__(16) _Float16 h1p[2][2][NB][72]; // [buf][plane][batch][unit(+pad)]
    __shared__ __align__(16) _Float16 h2p[2][2][NB][72];
    __shared__ __align__(16) _Float16 xp [4][2][NB][40]; // [slot][plane][batch][feat(+pad)]

    // ----- weights: unified slots shared by roles (hi plane only) -----
    // L0: slot0 = Wih0 (K=32 padded), slot1,2 = Whh0, slot3 zero (unused)
    // L1: slot0,1 = Wih1, slot2,3 = Whh1
    f16x8 Whi[4][4];
    f32x4 bias4[4];
    {
        float tmp[8];
        #pragma unroll
        for (int tau = 0; tau < 4; ++tau) {
            const int n = 64*tau + 16*w + mcol;
            if (isL0) {
                #pragma unroll
                for (int j=0;j<8;++j){ int k=8*c+j; tmp[j] = (k<NIN)? Wih0[n*NIN+k] : 0.0f; }
                cvt8h(tmp, Whi[tau][0]);
                #pragma unroll
                for (int kc=0;kc<2;++kc){
                    #pragma unroll
                    for (int j=0;j<8;++j) tmp[j] = Whh0[n*64 + 32*kc + 8*c + j];
                    cvt8h(tmp, Whi[tau][1+kc]);
                }
                #pragma unroll
                for (int j=0;j<8;++j) Whi[tau][3][j] = (_Float16)0.f;
            } else {
                #pragma unroll
                for (int kc=0;kc<2;++kc){
                    #pragma unroll
                    for (int j=0;j<8;++j) tmp[j] = Wih1[n*64 + 32*kc + 8*c + j];
                    cvt8h(tmp, Whi[tau][kc]);
                }
                #pragma unroll
                for (int kc=0;kc<2;++kc){
                    #pragma unroll
                    for (int j=0;j<8;++j) tmp[j] = Whh1[n*64 + 32*kc + 8*c + j];
                    cvt8h(tmp, Whi[tau][2+kc]);
                }
            }
            const int nb = 64*tau + 16*w + 4*c;
            #pragma unroll
            for (int v=0; v<4; ++v)
                bias4[tau][v] = 0.5f * (isL0 ? (bih0[nb+v] + bhh0[nb+v])
                                             : (bih1[nb+v] + bhh1[nb+v]));
        }
    }

    // ----- LDS zero init (full arrays incl. pads) -----
    {
        uint32_t* p1 = (uint32_t*)&h1p[0][0][0][0];   // 1152B = 288 u32
        uint32_t* p2 = (uint32_t*)&h2p[0][0][0][0];
        uint32_t* p3 = (uint32_t*)&xp[0][0][0][0];    // 1280B = 320 u32
        if (tid < 288){ p1[tid]=0u; p2[tid]=0u; }
        if (tid < 320){ p3[tid]=0u; }
    }
    __syncthreads();

    // ----- x staging: waves 0,1, lane<NIN -> (batch=wid, feat=lane) -----
    const bool stg = (wid < 2) && (lane < NIN);
    const float* xsrc = x + (size_t)(b0 + (wid & 1)) * T * NIN + lane;
    float xrA = 0.f, xrB = 0.f;
    if (stg){
        float x0 = xsrc[0], x1 = xsrc[NIN];
        _Float16 hh0 = (_Float16)x0;
        xp[0][0][wid][lane] = hh0;
        xp[0][1][wid][lane] = (_Float16)(x0 - (float)hh0);
        _Float16 hh1 = (_Float16)x1;
        xp[1][0][wid][lane] = hh1;
        xp[1][1][wid][lane] = (_Float16)(x1 - (float)hh1);
        xrA = xsrc[(size_t)2*NIN];
        xrB = xsrc[(size_t)3*NIN];
    }
    __syncthreads();

    // ----- B fragments: lane mcol<4 -> batch = mcol&1, plane = mcol>>1 -----
    f16x8 Bf[4];
    #pragma unroll
    for (int kc=0;kc<4;++kc)
        #pragma unroll
        for (int j=0;j<8;++j) Bf[kc][j] = (_Float16)0.f;
    if (isL0 && mcol < 4){
        Bf[0] = ldfrag(&xp[0][mcol>>1][mcol&1][8*c]);   // x(0); h slots stay 0
    }

    float cst = 0.f;   // c-state for this lane's (unit, batch)

    // ================= main loop: iter t = layer0(t) + layer1(t-1) ==========
    for (int t = 0; t <= T; ++t) {
        f32x4 a0 = bias4[0], a1 = bias4[1], a2 = bias4[2], a3 = bias4[3];
        #pragma unroll
        for (int kc=0; kc<4; ++kc){
            if (kc < 3 || !isL0) {     // wave-uniform: L0 has 3 chunks
                a0 = MFMA(Whi[0][kc], Bf[kc], a0);
                a1 = MFMA(Whi[1][kc], Bf[kc], a1);
                a2 = MFMA(Whi[2][kc], Bf[kc], a2);
                a3 = MFMA(Whi[3][kc], Bf[kc], a3);
            }
        }

        // spread D rows v=0..3 across lanes mcol = m' + 4v (verified row_shr),
        // then fold in cols m+2 (Hlo part) via row_ror:14 (lane i <- i+2).
        const int q = mcol >> 2;
        float g0, g1, g2, g3;
        {
            float u1, u2, u3;
            u1 = dppf<SHR4>(a0[1]); u2 = dppf<SHR8>(a0[2]); u3 = dppf<SHR12>(a0[3]);
            g0 = (q==0)? a0[0] : (q==1)? u1 : (q==2)? u2 : u3;
            u1 = dppf<SHR4>(a1[1]); u2 = dppf<SHR8>(a1[2]); u3 = dppf<SHR12>(a1[3]);
            g1 = (q==0)? a1[0] : (q==1)? u1 : (q==2)? u2 : u3;
            u1 = dppf<SHR4>(a2[1]); u2 = dppf<SHR8>(a2[2]); u3 = dppf<SHR12>(a2[3]);
            g2 = (q==0)? a2[0] : (q==1)? u1 : (q==2)? u2 : u3;
            u1 = dppf<SHR4>(a3[1]); u2 = dppf<SHR8>(a3[2]); u3 = dppf<SHR12>(a3[3]);
            g3 = (q==0)? a3[0] : (q==1)? u1 : (q==2)? u2 : u3;
            g0 += dppf<ROR14>(g0);
            g1 += dppf<ROR14>(g1);
            g2 += dppf<ROR14>(g2);
            g3 += dppf<ROR14>(g3);
        }

        const bool run = isL0 ? (t < T) : (t > 0);
        if (run && (mcol & 2) == 0) {          // 32 lanes: 16 units x 2 batches
            const int m = mcol & 1;
            const int u = 16*w + 4*c + q;
            float i_ = sigm(g0), f_ = sigm(g1);
            float gg = tanh_fast(g2), o_ = sigm(g3);
            cst = fmaf(f_, cst, i_ * gg);
            float h = o_ * tanh_fast(cst);
            _Float16 hh = (_Float16)h;
            _Float16 hl = (_Float16)(h - (float)hh);
            if (isL0){
                h1p[t & 1][0][m][u] = hh;
                h1p[t & 1][1][m][u] = hl;
            } else {
                h2p[(t-1) & 1][0][m][u] = hh;
                h2p[(t-1) & 1][1][m][u] = hl;
            }
        }

        // x staging: write x(t+2) (fetched 2 iters ago), issue x(t+4)
        if (stg){
            if (t + 2 < T){
                _Float16 hh = (_Float16)xrA;
                xp[(t+2)&3][0][wid][lane] = hh;
                xp[(t+2)&3][1][wid][lane] = (_Float16)(xrA - (float)hh);
            }
            xrA = xrB;
            if (t + 4 < T) xrB = xsrc[(size_t)(t+4)*NIN];
        }
        __syncthreads();

        // -------- rebuild B fragments for iteration t+1 (pure b128 reads) ----
        if (t < T && mcol < 4){
            const int bt = mcol & 1;
            const int p  = mcol >> 1;
            if (isL0){
                Bf[0] = ldfrag(&xp[(t+1)&3][p][bt][8*c]);
                Bf[1] = ldfrag(&h1p[t & 1][p][bt][8*c]);
                Bf[2] = ldfrag(&h1p[t & 1][p][bt][32 + 8*c]);
            } else {
                Bf[0] = ldfrag(&h1p[t & 1][p][bt][8*c]);
                Bf[1] = ldfrag(&h1p[t & 1][p][bt][32 + 8*c]);
                Bf[2] = ldfrag(&h2p[(t+1) & 1][p][bt][8*c]);        // h2(t-1)
                Bf[3] = ldfrag(&h2p[(t+1) & 1][p][bt][32 + 8*c]);
            }
        }
        // second barrier: no rebuild-read may overlap next iteration's writes
        // (r12 replay divergence was in this hazard class; r13 fixed it).
        __syncthreads();
    }

    // ---------------- FC epilogue: out[b] = dot(h2(T-1), Wfc) + bfc ----------
    if (wid < NB) {
        float hv = (float)h2p[(T-1) & 1][0][wid][lane]
                 + (float)h2p[(T-1) & 1][1][wid][lane];
        float val = hv * Wfc[lane];
        #pragma unroll
        for (int off = 32; off > 0; off >>= 1)
            val += __shfl_down(val, off, 64);
        if (lane == 0) out[b0 + wid] = val + bfc[0];
    }
}

} // namespace

extern "C" void kernel_launch(void* const* d_in, const int* in_sizes, int n_in,
                              void* d_out, int out_size, void* d_ws, size_t ws_size,
                              hipStream_t stream)
{
    const float* x    = (const float*)d_in[0];
    const float* Wih0 = (const float*)d_in[1];
    const float* Whh0 = (const float*)d_in[2];
    const float* bih0 = (const float*)d_in[3];
    const float* bhh0 = (const float*)d_in[4];
    const float* Wih1 = (const float*)d_in[5];
    const float* Whh1 = (const float*)d_in[6];
    const float* bih1 = (const float*)d_in[7];
    const float* bhh1 = (const float*)d_in[8];
    const float* Wfc  = (const float*)d_in[9];
    const float* bfc  = (const float*)d_in[10];
    float* out = (float*)d_out;

    hipLaunchKernelGGL(lstm_mf6, dim3(512 / NB), dim3(512), 0, stream,
                       x, Wih0, Whh0, bih0, bhh0, Wih1, Whh1, bih1, bhh1,
                       Wfc, bfc, out);
}

// Round 16
// 1858.998 us; speedup vs baseline: 1.3766x; 1.1591x over previous
//
#include <hip/hip_runtime.h>
#include <stdint.h>

namespace {

constexpr int NIN = 21;
constexpr int T   = 3000;
constexpr int NB  = 2;     // batches per block -> 256 blocks = 1 per CU

typedef _Float16 f16x8 __attribute__((ext_vector_type(8)));
typedef float    f32x4 __attribute__((ext_vector_type(4)));

__device__ __forceinline__ float frcp(float x){ return __builtin_amdgcn_rcpf(x); }
__device__ __forceinline__ float sigm(float v){ return frcp(1.0f + __expf(-v)); }
__device__ __forceinline__ float tanh_fast(float v){
    return fmaf(-2.0f, frcp(__expf(2.0f*v) + 1.0f), 1.0f);
}

template<int CTRL>
__device__ __forceinline__ float dppf(float v){
    return __int_as_float(__builtin_amdgcn_update_dpp(
        0, __float_as_int(v), CTRL, 0xF, 0xF, true));
}
// Verified family: row_ror:J => out[i] = in[(i-J)&15]; row_shr:N => out[i] = in[i-N]
constexpr int SHR4  = 0x114;
constexpr int SHR8  = 0x118;
constexpr int SHR12 = 0x11C;
constexpr int ROR14 = 0x12E;   // out[i] = in[(i+2)&15]

#define MFMA(A,B,C) __builtin_amdgcn_mfma_f32_16x16x32_f16((A),(B),(C),0,0,0)

__device__ __forceinline__ f16x8 ldfrag(const _Float16* p){
    return *reinterpret_cast<const f16x8*>(p);   // aligned 16B LDS read
}
__device__ __forceinline__ void cvt8h(const float* s, f16x8& hi){
    #pragma unroll
    for (int j=0;j<8;++j) hi[j] = (_Float16)s[j];
}

// Verified MFMA layout (r8-r15): D[n][m] = sum_k A[n][k]*B[m][k]
//   A-frag: n = lane&15, k = 32*kc + 8*(lane>>4) + j ; B same
//   D:      m = lane&15, n = 4*(lane>>4) + v
// B cols: 0,1 = batch0/1 Hhi; 2,3 = batch0/1 Hlo; >=4 zero.
// W is f16 hi-only (r15, absmax 4.9e-4). gate = D[:,m] + D[:,m+2] = Whi·(Hhi+Hlo).
// Bias halved in C-init (both summed columns carry it).
__launch_bounds__(512, 2)
__global__ void lstm_mf7(const float* __restrict__ x,
                         const float* __restrict__ Wih0, const float* __restrict__ Whh0,
                         const float* __restrict__ bih0, const float* __restrict__ bhh0,
                         const float* __restrict__ Wih1, const float* __restrict__ Whh1,
                         const float* __restrict__ bih1, const float* __restrict__ bhh1,
                         const float* __restrict__ Wfc,  const float* __restrict__ bfc,
                         float* __restrict__ out)
{
    const int tid  = threadIdx.x;
    const int lane = tid & 63;
    const int wid  = tid >> 6;
    const int c    = lane >> 4;     // k-subchunk 0..3
    const int mcol = lane & 15;
    const int b0   = blockIdx.x * NB;
    const bool isL0 = (wid < 4);
    const int  w    = wid & 3;      // unit range [16w, 16w+16)

    __shared__ __align__(16) _Float16 h1p[2][2][NB][72]; // [buf][plane][batch][unit(+pad)]
    __shared__ __align__(16) _Float16 h2p[2][2][NB][72];
    __shared__ __align__(16) _Float16 xp [4][2][NB][40]; // [slot][plane][batch][feat(+pad)]

    // ----- weights: unified slots shared by roles (hi plane only) -----
    f16x8 Whi[4][4];
    f32x4 bias4[4];
    {
        float tmp[8];
        #pragma unroll
        for (int tau = 0; tau < 4; ++tau) {
            const int n = 64*tau + 16*w + mcol;
            if (isL0) {
                #pragma unroll
                for (int j=0;j<8;++j){ int k=8*c+j; tmp[j] = (k<NIN)? Wih0[n*NIN+k] : 0.0f; }
                cvt8h(tmp, Whi[tau][0]);
                #pragma unroll
                for (int kc=0;kc<2;++kc){
                    #pragma unroll
                    for (int j=0;j<8;++j) tmp[j] = Whh0[n*64 + 32*kc + 8*c + j];
                    cvt8h(tmp, Whi[tau][1+kc]);
                }
                #pragma unroll
                for (int j=0;j<8;++j) Whi[tau][3][j] = (_Float16)0.f;
            } else {
                #pragma unroll
                for (int kc=0;kc<2;++kc){
                    #pragma unroll
                    for (int j=0;j<8;++j) tmp[j] = Wih1[n*64 + 32*kc + 8*c + j];
                    cvt8h(tmp, Whi[tau][kc]);
                }
                #pragma unroll
                for (int kc=0;kc<2;++kc){
                    #pragma unroll
                    for (int j=0;j<8;++j) tmp[j] = Whh1[n*64 + 32*kc + 8*c + j];
                    cvt8h(tmp, Whi[tau][2+kc]);
                }
            }
            const int nb = 64*tau + 16*w + 4*c;
            #pragma unroll
            for (int v=0; v<4; ++v)
                bias4[tau][v] = 0.5f * (isL0 ? (bih0[nb+v] + bhh0[nb+v])
                                             : (bih1[nb+v] + bhh1[nb+v]));
        }
    }

    // ----- LDS zero init -----
    {
        uint32_t* p1 = (uint32_t*)&h1p[0][0][0][0];   // 288 u32
        uint32_t* p2 = (uint32_t*)&h2p[0][0][0][0];
        uint32_t* p3 = (uint32_t*)&xp[0][0][0][0];    // 320 u32
        if (tid < 288){ p1[tid]=0u; p2[tid]=0u; }
        if (tid < 320){ p3[tid]=0u; }
    }
    __syncthreads();

    // ----- x staging: waves 0,1, lane<NIN -> (batch=wid, feat=lane) -----
    const bool stg = (wid < 2) && (lane < NIN);
    const float* xsrc = x + (size_t)(b0 + (wid & 1)) * T * NIN + lane;
    float xrA = 0.f, xrB = 0.f;
    if (stg){
        float x0 = xsrc[0], x1 = xsrc[NIN];
        _Float16 hh0 = (_Float16)x0;
        xp[0][0][wid][lane] = hh0;
        xp[0][1][wid][lane] = (_Float16)(x0 - (float)hh0);
        _Float16 hh1 = (_Float16)x1;
        xp[1][0][wid][lane] = hh1;
        xp[1][1][wid][lane] = (_Float16)(x1 - (float)hh1);
        xrA = xsrc[(size_t)2*NIN];
        xrB = xsrc[(size_t)3*NIN];
    }
    __syncthreads();

    // ----- B fragments: lane mcol<4 -> batch = mcol&1, plane = mcol>>1 -----
    f16x8 Bf[4];
    #pragma unroll
    for (int kc=0;kc<4;++kc)
        #pragma unroll
        for (int j=0;j<8;++j) Bf[kc][j] = (_Float16)0.f;
    if (isL0 && mcol < 4){
        Bf[0] = ldfrag(&xp[0][mcol>>1][mcol&1][8*c]);   // x(0); h slots stay 0
    }

    float cst = 0.f;
    const int q   = mcol >> 2;
    const int m   = mcol & 1;
    const int pl  = (mcol >> 1) & 1;
    const int u   = 16*w + 4*c + q;
    const bool pw = ((mcol & 2) == 0);

    // ====== main loop: 750 x 4 phases; t = tb+ph in [0, T) ; tb%4==0 ======
    // slot arithmetic: t&1 == ph&1, t&3 == ph&3 (compile-time after unroll)
    for (int tb = 0; tb < T; tb += 4) {
        #pragma unroll
        for (int ph = 0; ph < 4; ++ph) {
            const int t = tb + ph;
            // issue x global load for t+4 early
            float xnew = 0.f;
            if (stg && (t + 4 < T)) xnew = xsrc[(size_t)(t+4)*NIN];

            // -------- MFMA (uses Bf rebuilt at end of previous phase) --------
            f32x4 a0 = bias4[0], a1 = bias4[1], a2 = bias4[2], a3 = bias4[3];
            if (isL0) {
                #pragma unroll
                for (int kc=0; kc<3; ++kc){
                    a0 = MFMA(Whi[0][kc], Bf[kc], a0);
                    a1 = MFMA(Whi[1][kc], Bf[kc], a1);
                    a2 = MFMA(Whi[2][kc], Bf[kc], a2);
                    a3 = MFMA(Whi[3][kc], Bf[kc], a3);
                }
            } else {
                #pragma unroll
                for (int kc=0; kc<4; ++kc){
                    a0 = MFMA(Whi[0][kc], Bf[kc], a0);
                    a1 = MFMA(Whi[1][kc], Bf[kc], a1);
                    a2 = MFMA(Whi[2][kc], Bf[kc], a2);
                    a3 = MFMA(Whi[3][kc], Bf[kc], a3);
                }
            }

            // -------- spread rows to lanes, fold Hlo cols (verified) --------
            float g0, g1, g2, g3;
            {
                float u1, u2, u3;
                u1 = dppf<SHR4>(a0[1]); u2 = dppf<SHR8>(a0[2]); u3 = dppf<SHR12>(a0[3]);
                g0 = (q==0)? a0[0] : (q==1)? u1 : (q==2)? u2 : u3;
                u1 = dppf<SHR4>(a1[1]); u2 = dppf<SHR8>(a1[2]); u3 = dppf<SHR12>(a1[3]);
                g1 = (q==0)? a1[0] : (q==1)? u1 : (q==2)? u2 : u3;
                u1 = dppf<SHR4>(a2[1]); u2 = dppf<SHR8>(a2[2]); u3 = dppf<SHR12>(a2[3]);
                g2 = (q==0)? a2[0] : (q==1)? u1 : (q==2)? u2 : u3;
                u1 = dppf<SHR4>(a3[1]); u2 = dppf<SHR8>(a3[2]); u3 = dppf<SHR12>(a3[3]);
                g3 = (q==0)? a3[0] : (q==1)? u1 : (q==2)? u2 : u3;
                g0 += dppf<ROR14>(g0);
                g1 += dppf<ROR14>(g1);
                g2 += dppf<ROR14>(g2);
                g3 += dppf<ROR14>(g3);
            }

            // -------- pointwise: compute h in registers (no LDS write yet) ---
            const bool dow = pw && (isL0 || t > 0);
            _Float16 hh = (_Float16)0.f, hl = (_Float16)0.f;
            if (dow) {
                float i_ = sigm(g0), f_ = sigm(g1);
                float gg = tanh_fast(g2), o_ = sigm(g3);
                cst = fmaf(f_, cst, i_ * gg);
                float h = o_ * tanh_fast(cst);
                hh = (_Float16)h;
                hl = (_Float16)(h - (float)hh);
            }

            // BW: all waves finished their rebuild READS (done ~600cy ago) ----
            __syncthreads();

            // -------- writes --------
            if (dow) {
                if (isL0){
                    h1p[ph & 1][0][m][u] = hh;
                    h1p[ph & 1][1][m][u] = hl;
                } else {
                    h2p[(ph+1) & 1][0][m][u] = hh;
                    h2p[(ph+1) & 1][1][m][u] = hl;
                }
            }
            if (stg){
                if (t + 2 < T){
                    _Float16 xh = (_Float16)xrA;
                    xp[(ph+2) & 3][0][wid][lane] = xh;
                    xp[(ph+2) & 3][1][wid][lane] = (_Float16)(xrA - (float)xh);
                }
                xrA = xrB; xrB = xnew;
            }

            // BR: writes visible ---------------------------------------------
            __syncthreads();

            // -------- rebuild B fragments for t+1 (pure b128 reads) ---------
            if (mcol < 4){
                if (isL0){
                    Bf[0] = ldfrag(&xp[(ph+1) & 3][pl][m][8*c]);
                    Bf[1] = ldfrag(&h1p[ph & 1][pl][m][8*c]);
                    Bf[2] = ldfrag(&h1p[ph & 1][pl][m][32 + 8*c]);
                } else {
                    Bf[0] = ldfrag(&h1p[ph & 1][pl][m][8*c]);
                    Bf[1] = ldfrag(&h1p[ph & 1][pl][m][32 + 8*c]);
                    Bf[2] = ldfrag(&h2p[(ph+1) & 1][pl][m][8*c]);       // h2(t-1)
                    Bf[3] = ldfrag(&h2p[(ph+1) & 1][pl][m][32 + 8*c]);
                }
            }
        }
    }

    // ====== epilogue t=T: layer1 computes step T-1 ======
    if (!isL0) {
        f32x4 a0 = bias4[0], a1 = bias4[1], a2 = bias4[2], a3 = bias4[3];
        #pragma unroll
        for (int kc=0; kc<4; ++kc){
            a0 = MFMA(Whi[0][kc], Bf[kc], a0);
            a1 = MFMA(Whi[1][kc], Bf[kc], a1);
            a2 = MFMA(Whi[2][kc], Bf[kc], a2);
            a3 = MFMA(Whi[3][kc], Bf[kc], a3);
        }
        float g0, g1, g2, g3;
        {
            float u1, u2, u3;
            u1 = dppf<SHR4>(a0[1]); u2 = dppf<SHR8>(a0[2]); u3 = dppf<SHR12>(a0[3]);
            g0 = (q==0)? a0[0] : (q==1)? u1 : (q==2)? u2 : u3;
            u1 = dppf<SHR4>(a1[1]); u2 = dppf<SHR8>(a1[2]); u3 = dppf<SHR12>(a1[3]);
            g1 = (q==0)? a1[0] : (q==1)? u1 : (q==2)? u2 : u3;
            u1 = dppf<SHR4>(a2[1]); u2 = dppf<SHR8>(a2[2]); u3 = dppf<SHR12>(a2[3]);
            g2 = (q==0)? a2[0] : (q==1)? u1 : (q==2)? u2 : u3;
            u1 = dppf<SHR4>(a3[1]); u2 = dppf<SHR8>(a3[2]); u3 = dppf<SHR12>(a3[3]);
            g3 = (q==0)? a3[0] : (q==1)? u1 : (q==2)? u2 : u3;
            g0 += dppf<ROR14>(g0);
            g1 += dppf<ROR14>(g1);
            g2 += dppf<ROR14>(g2);
            g3 += dppf<ROR14>(g3);
        }
        if (pw) {
            float i_ = sigm(g0), f_ = sigm(g1);
            float gg = tanh_fast(g2), o_ = sigm(g3);
            cst = fmaf(f_, cst, i_ * gg);
            float h = o_ * tanh_fast(cst);
            _Float16 hh = (_Float16)h;
            h2p[(T-1) & 1][0][m][u] = hh;
            h2p[(T-1) & 1][1][m][u] = (_Float16)(h - (float)hh);
        }
    }
    __syncthreads();

    // ---------------- FC epilogue: out[b] = dot(h2(T-1), Wfc) + bfc ----------
    if (wid < NB) {
        float hv = (float)h2p[(T-1) & 1][0][wid][lane]
                 + (float)h2p[(T-1) & 1][1][wid][lane];
        float val = hv * Wfc[lane];
        #pragma unroll
        for (int off = 32; off > 0; off >>= 1)
            val += __shfl_down(val, off, 64);
        if (lane == 0) out[b0 + wid] = val + bfc[0];
    }
}

} // namespace

extern "C" void kernel_launch(void* const* d_in, const int* in_sizes, int n_in,
                              void* d_out, int out_size, void* d_ws, size_t ws_size,
                              hipStream_t stream)
{
    const float* x    = (const float*)d_in[0];
    const float* Wih0 = (const float*)d_in[1];
    const float* Whh0 = (const float*)d_in[2];
    const float* bih0 = (const float*)d_in[3];
    const float* bhh0 = (const float*)d_in[4];
    const float* Wih1 = (const float*)d_in[5];
    const float* Whh1 = (const float*)d_in[6];
    const float* bih1 = (const float*)d_in[7];
    const float* bhh1 = (const float*)d_in[8];
    const float* Wfc  = (const float*)d_in[9];
    const float* bfc  = (const float*)d_in[10];
    float* out = (float*)d_out;

    hipLaunchKernelGGL(lstm_mf7, dim3(512 / NB), dim3(512), 0, stream,
                       x, Wih0, Whh0, bih0, bhh0, Wih1, Whh1, bih1, bhh1,
                       Wfc, bfc, out);
}